// Round 5
// baseline (1608.387 us; speedup 1.0000x reference)
//
#include <hip/hip_runtime.h>
#include <hip/hip_cooperative_groups.h>
#include <cstdint>
#include <cstddef>

namespace cg = cooperative_groups;

#define T_ 2048
#define OBS_ 512
#define MLP_ 1024
#define H_ 1024
#define ACT_ 16
#define H3_ 3072

typedef short bf16x8 __attribute__((ext_vector_type(8)));
typedef float f32x4 __attribute__((ext_vector_type(4)));

// ---------------------------------------------------------------------------
// threefry2x32 (JAX/XLA exact)
// ---------------------------------------------------------------------------
__host__ __device__ __forceinline__ uint32_t rotl32(uint32_t v, int d) {
  return (v << d) | (v >> (32 - d));
}
__host__ __device__ __forceinline__ void tf2x32(uint32_t k0, uint32_t k1,
                                                uint32_t x0, uint32_t x1,
                                                uint32_t& o0, uint32_t& o1) {
  uint32_t ks2 = k0 ^ k1 ^ 0x1BD11BDAu;
  x0 += k0; x1 += k1;
  x0 += x1; x1 = rotl32(x1, 13); x1 ^= x0;
  x0 += x1; x1 = rotl32(x1, 15); x1 ^= x0;
  x0 += x1; x1 = rotl32(x1, 26); x1 ^= x0;
  x0 += x1; x1 = rotl32(x1, 6);  x1 ^= x0;
  x0 += k1; x1 += ks2 + 1u;
  x0 += x1; x1 = rotl32(x1, 17); x1 ^= x0;
  x0 += x1; x1 = rotl32(x1, 29); x1 ^= x0;
  x0 += x1; x1 = rotl32(x1, 16); x1 ^= x0;
  x0 += x1; x1 = rotl32(x1, 24); x1 ^= x0;
  x0 += ks2; x1 += k0 + 2u;
  x0 += x1; x1 = rotl32(x1, 13); x1 ^= x0;
  x0 += x1; x1 = rotl32(x1, 15); x1 ^= x0;
  x0 += x1; x1 = rotl32(x1, 26); x1 ^= x0;
  x0 += x1; x1 = rotl32(x1, 6);  x1 ^= x0;
  x0 += k0; x1 += k1 + 3u;
  x0 += x1; x1 = rotl32(x1, 17); x1 ^= x0;
  x0 += x1; x1 = rotl32(x1, 29); x1 ^= x0;
  x0 += x1; x1 = rotl32(x1, 16); x1 ^= x0;
  x0 += x1; x1 = rotl32(x1, 24); x1 ^= x0;
  x0 += k1; x1 += ks2 + 4u;
  x0 += x1; x1 = rotl32(x1, 13); x1 ^= x0;
  x0 += x1; x1 = rotl32(x1, 15); x1 ^= x0;
  x0 += x1; x1 = rotl32(x1, 26); x1 ^= x0;
  x0 += x1; x1 = rotl32(x1, 6);  x1 ^= x0;
  x0 += ks2; x1 += k0 + 5u;
  o0 = x0; o1 = x1;
}

// XLA ErfInv32 (Giles)
__device__ __forceinline__ float erfinv_f32(float x) {
  float w = -log1pf(-x * x);
  float p;
  if (w < 5.0f) {
    w = w - 2.5f;
    p = 2.81022636e-08f;
    p = fmaf(p, w, 3.43273939e-07f);
    p = fmaf(p, w, -3.5233877e-06f);
    p = fmaf(p, w, -4.39150654e-06f);
    p = fmaf(p, w, 0.00021858087f);
    p = fmaf(p, w, -0.00125372503f);
    p = fmaf(p, w, -0.00417768164f);
    p = fmaf(p, w, 0.246640727f);
    p = fmaf(p, w, 1.50140941f);
  } else {
    w = sqrtf(w) - 3.0f;
    p = -0.000200214257f;
    p = fmaf(p, w, 0.000100950558f);
    p = fmaf(p, w, 0.00134934322f);
    p = fmaf(p, w, -0.00367342844f);
    p = fmaf(p, w, 0.00573950773f);
    p = fmaf(p, w, -0.0076224613f);
    p = fmaf(p, w, 0.00943887047f);
    p = fmaf(p, w, 1.00167406f);
    p = fmaf(p, w, 2.83297682f);
  }
  return p * x;
}

__device__ __forceinline__ float bits_to_normal(uint32_t bits) {
  const float lo = -0.99999994f;
  float f = __uint_as_float((bits >> 9) | 0x3f800000u) - 1.0f;
  float u = fmaf(f, 2.0f, lo);
  u = fmaxf(lo, u);
  return 1.41421356237f * erfinv_f32(u);
}

__device__ __forceinline__ float sigmoidf_(float x) {
  return 1.0f / (1.0f + expf(-x));
}
__device__ __forceinline__ float mishf_(float x) {
  float sp = fmaxf(x, 0.0f) + log1pf(expf(-fabsf(x)));
  return x * tanhf(sp);
}

// bf16 RNE split helpers
__device__ __forceinline__ ushort f2bf(float v) {
  uint32_t u = __float_as_uint(v);
  uint32_t r = (u + 0x7FFFu + ((u >> 16) & 1u)) >> 16;
  return (ushort)r;
}
__device__ __forceinline__ float bf2f(ushort b) {
  return __uint_as_float(((uint32_t)b) << 16);
}

// ---------------------------------------------------------------------------
// Noise: v = wm + ws*normal; weights -> hi/lo bf16, biases -> fp32.
// Also zeroes meta (counts+cursors, 4096 ints) in first 16 blocks.
// ---------------------------------------------------------------------------
struct NoiseDesc {
  const float* wm; const float* ws;
  ushort* dh; ushort* dl; float* df;
  uint32_t k0, k1, base, mode;
};
struct NoiseArgs { NoiseDesc d[8]; uint32_t total; int* meta_zero; };

__global__ __launch_bounds__(256) void k_gen_noise(NoiseArgs a) {
  if (blockIdx.x < 16) a.meta_zero[blockIdx.x * 256 + threadIdx.x] = 0;
  uint32_t idx = blockIdx.x * 256u + threadIdx.x;
  for (; idx < a.total; idx += gridDim.x * 256u) {
    int ti = 0;
#pragma unroll
    for (int i = 1; i < 8; ++i) if (idx >= a.d[i].base) ti = i;
    NoiseDesc dd = a.d[ti];
    uint32_t j = idx - dd.base;
    uint32_t b1, b2;
    tf2x32(dd.k0, dd.k1, 0u, j, b1, b2);
    float v = fmaf(dd.ws[j], bits_to_normal(b1 ^ b2), dd.wm[j]);
    if (dd.mode) {
      ushort hb = f2bf(v);
      dd.dh[j] = hb;
      dd.dl[j] = f2bf(v - bf2f(hb));
    } else {
      dd.df[j] = v;
    }
  }
}

// fp32 -> (hi, lo) bf16 split, vectorized
__global__ __launch_bounds__(256) void k_split(const float* __restrict__ in,
                                               ushort* __restrict__ h,
                                               ushort* __restrict__ l, int n4) {
  int i = blockIdx.x * 256 + threadIdx.x;
  if (i >= n4) return;
  float4 v = ((const float4*)in)[i];
  ushort4 hb, lb;
  hb.x = f2bf(v.x); lb.x = f2bf(v.x - bf2f(hb.x));
  hb.y = f2bf(v.y); lb.y = f2bf(v.y - bf2f(hb.y));
  hb.z = f2bf(v.z); lb.z = f2bf(v.z - bf2f(hb.z));
  hb.w = f2bf(v.w); lb.w = f2bf(v.w - bf2f(hb.w));
  ((ushort4*)h)[i] = hb;
  ((ushort4*)l)[i] = lb;
}

// ---------------------------------------------------------------------------
// MFMA split-bf16 GEMM (feed-forward; unchanged — verified r3/r4).
// ---------------------------------------------------------------------------
template <int ACTF, int OUTM>
__global__ __launch_bounds__(256, 2) void k_mgemm(
    const ushort* __restrict__ Ah, const ushort* __restrict__ Al,
    const ushort* __restrict__ Wh, const ushort* __restrict__ Wl,
    const float* __restrict__ bias,
    float* __restrict__ Cf, ushort* __restrict__ Ch, ushort* __restrict__ Cl,
    int K, int Nreal, int ldc) {
  __shared__ ushort sA[2][128 * 32];
  __shared__ ushort sW[2][128 * 32];
  const int tid = threadIdx.x;
  const int m0 = blockIdx.y * 128, n0 = blockIdx.x * 128;
  const int wid = tid >> 6, lane = tid & 63;
  const int wm = (wid >> 1) * 64, wn = (wid & 1) * 64;
  const int lr = lane & 15, lk = lane >> 4;
  const int r0 = tid >> 2;
  const int c0 = (tid & 3) * 8;
  f32x4 acc[4][4] = {};
  for (int k0 = 0; k0 < K; k0 += 32) {
    const size_t aoff0 = (size_t)(m0 + r0) * K + k0 + c0;
    const size_t aoff1 = (size_t)(m0 + r0 + 64) * K + k0 + c0;
    const size_t woff0 = (size_t)(n0 + r0) * K + k0 + c0;
    const size_t woff1 = (size_t)(n0 + r0 + 64) * K + k0 + c0;
    int4 ah0 = *(const int4*)(Ah + aoff0);
    int4 ah1 = *(const int4*)(Ah + aoff1);
    int4 al0 = *(const int4*)(Al + aoff0);
    int4 al1 = *(const int4*)(Al + aoff1);
    int4 wh0 = *(const int4*)(Wh + woff0);
    int4 wh1 = *(const int4*)(Wh + woff1);
    int4 wl0 = *(const int4*)(Wl + woff0);
    int4 wl1 = *(const int4*)(Wl + woff1);
    __syncthreads();
    *(int4*)(&sA[0][r0 * 32 + c0]) = ah0;
    *(int4*)(&sA[0][(r0 + 64) * 32 + c0]) = ah1;
    *(int4*)(&sA[1][r0 * 32 + c0]) = al0;
    *(int4*)(&sA[1][(r0 + 64) * 32 + c0]) = al1;
    *(int4*)(&sW[0][r0 * 32 + c0]) = wh0;
    *(int4*)(&sW[0][(r0 + 64) * 32 + c0]) = wh1;
    *(int4*)(&sW[1][r0 * 32 + c0]) = wl0;
    *(int4*)(&sW[1][(r0 + 64) * 32 + c0]) = wl1;
    __syncthreads();
    bf16x8 fah[4], fal[4], fwh[4], fwl[4];
#pragma unroll
    for (int f = 0; f < 4; ++f) {
      int ar = (wm + f * 16 + lr) * 32 + lk * 8;
      fah[f] = *(const bf16x8*)(&sA[0][ar]);
      fal[f] = *(const bf16x8*)(&sA[1][ar]);
      int wr = (wn + f * 16 + lr) * 32 + lk * 8;
      fwh[f] = *(const bf16x8*)(&sW[0][wr]);
      fwl[f] = *(const bf16x8*)(&sW[1][wr]);
    }
#pragma unroll
    for (int mf = 0; mf < 4; ++mf)
#pragma unroll
      for (int nf = 0; nf < 4; ++nf) {
        acc[mf][nf] = __builtin_amdgcn_mfma_f32_16x16x32_bf16(fah[mf], fwh[nf], acc[mf][nf], 0, 0, 0);
        acc[mf][nf] = __builtin_amdgcn_mfma_f32_16x16x32_bf16(fah[mf], fwl[nf], acc[mf][nf], 0, 0, 0);
        acc[mf][nf] = __builtin_amdgcn_mfma_f32_16x16x32_bf16(fal[mf], fwh[nf], acc[mf][nf], 0, 0, 0);
      }
  }
#pragma unroll
  for (int mf = 0; mf < 4; ++mf)
#pragma unroll
    for (int nf = 0; nf < 4; ++nf) {
      int col = n0 + wn + nf * 16 + lr;
      if (col >= Nreal) continue;
      float bv = bias[col];
#pragma unroll
      for (int r = 0; r < 4; ++r) {
        int row = m0 + wm + mf * 16 + lk * 4 + r;
        float v = acc[mf][nf][r] + bv;
        if (ACTF) v = mishf_(v);
        if (OUTM == 0) {
          Cf[(size_t)row * ldc + col] = v;
        } else {
          ushort hb = f2bf(v);
          Ch[(size_t)row * ldc + col] = hb;
          Cl[(size_t)row * ldc + col] = f2bf(v - bf2f(hb));
        }
      }
    }
}

// ---------------------------------------------------------------------------
// Cooperative fused GRU scan, MFMA rounds with fused gating epilogue.
// grid = 256 * blocksPerCU (occupancy-queried), 256 threads (4 waves).
// Tile: 64 timesteps x 32 i (x3 gates), K-chunk 32, 2-deep prefetch,
// whh pre-split to bf16 hi/lo. States stored as hi/lo bf16.
// ---------------------------------------------------------------------------
struct SMemScan {
  union {
    struct {
      ushort Hs[2][64][40];   // [hi/lo][t-slot][k], row stride 80B (2-way free)
      ushort Bs[2][96][40];   // [hi/lo][g*32+ii][k]
    } mm;
    int scan[2][2048];
  } u;
  int tl[64];
};

__global__ __launch_bounds__(256) void k_scan(
    const float* __restrict__ ig, const float* __restrict__ whhf,
    const ushort* __restrict__ whh_h, const ushort* __restrict__ whh_l,
    const float* __restrict__ gbn, const float* __restrict__ state0,
    const int* __restrict__ start, int* __restrict__ counts,
    int* __restrict__ cursors, int* __restrict__ li_,
    int* __restrict__ offsets, int* __restrict__ list,
    ushort* __restrict__ st_h, ushort* __restrict__ st_l,
    float* __restrict__ hg0) {
  cg::grid_group grid = cg::this_grid();
  __shared__ SMemScan sm;
  const int tid = threadIdx.x, bid = blockIdx.x, nb = gridDim.x;
  const float keep0 = 1.0f - (float)start[0];

  // P1: local index + counts (counts pre-zeroed by noise kernel)
  if (bid < 8) {
    int t = bid * 256 + tid;
    int l = 0, tt = t;
    while (tt > 0 && start[tt] == 0) { tt--; l++; }
    li_[t] = l;
    if (t > 0) atomicAdd(&counts[l], 1);
  }
  grid.sync();

  // P2: exclusive prefix sum of counts -> offsets (block 0)
  if (bid == 0) {
    for (int i = tid; i < 2048; i += 256) sm.u.scan[0][i] = counts[i];
    __syncthreads();
    int cur = 0;
    for (int d = 1; d < 2048; d <<= 1) {
      int nx = cur ^ 1;
      for (int i = tid; i < 2048; i += 256)
        sm.u.scan[nx][i] = sm.u.scan[cur][i] + (i >= d ? sm.u.scan[cur][i - d] : 0);
      __syncthreads();
      cur = nx;
    }
    for (int i = tid; i < 2048; i += 256)
      offsets[i] = (i == 0) ? 0 : sm.u.scan[cur][i - 1];
  }
  grid.sync();

  // P3: scatter t's into per-round lists; P4: hg0 = (state0*keep0) @ whh^T
  if (bid < 8) {
    int t = bid * 256 + tid;
    if (t > 0) {
      int l = li_[t];
      int pos = atomicAdd(&cursors[l], 1);
      list[offsets[l] + pos] = t;
    }
  }
  {
    int gw = bid * 4 + (tid >> 6);
    int lane = tid & 63;
    for (int r = gw * 3; r < gw * 3 + 3 && r < H3_; ++r) {
      const float* wr = whhf + (size_t)r * H_;
      float s = 0.f;
      for (int c = lane; c < H_; c += 64) s = fmaf(wr[c], state0[c] * keep0, s);
      for (int o = 32; o; o >>= 1) s += __shfl_down(s, o, 64);
      if (lane == 0) hg0[r] = s;
    }
  }
  grid.sync();

  // P5: round 0 gating (all segment starts + t=0)
  {
    int cnt0 = counts[0];
    int off0 = offsets[0];
    int total = (cnt0 + 1) * H_;
    for (int e = bid * 256 + tid; e < total; e += nb * 256) {
      int s = e >> 10, i = e & (H_ - 1);
      int t; float hin, hr, hz, hn;
      if (s == 0) {
        t = 0; hin = state0[i] * keep0;
        hr = hg0[i]; hz = hg0[H_ + i]; hn = hg0[2 * H_ + i];
      } else {
        t = list[off0 + s - 1]; hin = 0.f; hr = 0.f; hz = 0.f; hn = 0.f;
      }
      float ir = ig[(size_t)t * H3_ + i];
      float iz = ig[(size_t)t * H3_ + H_ + i];
      float in_ = ig[(size_t)t * H3_ + 2 * H_ + i];
      float r = sigmoidf_(ir + hr), u = sigmoidf_(iz + hz);
      float n = tanhf(in_ + r * (hn + gbn[i]));
      float v = n + u * (hin - n);
      ushort hb = f2bf(v);
      st_h[(size_t)t * H_ + i] = hb;
      st_l[(size_t)t * H_ + i] = f2bf(v - bf2f(hb));
    }
  }
  grid.sync();

  // P6: rounds k >= 1 — MFMA GEMM tiles with fused gating epilogue
  const int wid = tid >> 6, lane = tid & 63;
  const int lr = lane & 15, lk = lane >> 4;
  const int wm = (wid >> 1) * 32;  // m-half: 0 or 32
  const int wi = wid & 1;          // i-half within 32-i tile

  // staging cell decode (thread-invariant)
  const int a_koct = tid & 3, a_row = (tid >> 2) & 63;
  int blev[3], brow[3], bkoct[3];
#pragma unroll
  for (int j = 0; j < 3; ++j) {
    int c = tid + 256 * j;          // 0..767: lev*384 + row*4 + koct
    blev[j] = c / 384;
    int rem = c - blev[j] * 384;
    brow[j] = rem >> 2;
    bkoct[j] = rem & 3;
  }
  const ushort* bsp[3];
#pragma unroll
  for (int j = 0; j < 3; ++j) bsp[j] = blev[j] ? whh_l : whh_h;

  for (int k = 1; k < 2048; ++k) {
    int cnt = counts[k];
    if (cnt == 0) break;
    int off = offsets[k];
    int mtiles = (cnt + 63) >> 6;
    int tiles = mtiles << 5;   // x32 i-tiles of 32 i's
    for (int tile = bid; tile < tiles; tile += nb) {
      int mt = tile >> 5;
      int i0 = (tile & 31) << 5;
      __syncthreads();
      if (tid < 64) {
        int s = mt * 64 + tid;
        sm.tl[tid] = (s < cnt) ? list[off + s] : 0;  // 0 = invalid slot
      }
      __syncthreads();

      size_t bsrc[3];
#pragma unroll
      for (int j = 0; j < 3; ++j)
        bsrc[j] = (size_t)((brow[j] >> 5) * H_ + i0 + (brow[j] & 31)) * H_ + bkoct[j] * 8;

      f32x4 acc[2][3] = {};
      int4 paA[2], paB[2], pbA[3], pbB[3];

#define LOADA(K0, DST)                                                        \
      {                                                                       \
        int t0_ = sm.tl[a_row];                                               \
        DST[0] = make_int4(0, 0, 0, 0); DST[1] = make_int4(0, 0, 0, 0);       \
        if (t0_ > 0) {                                                        \
          size_t base_ = (size_t)(t0_ - 1) * H_ + (K0) + a_koct * 8;          \
          DST[0] = *(const int4*)(st_h + base_);                              \
          DST[1] = *(const int4*)(st_l + base_);                              \
        }                                                                     \
      }
#define LOADB(K0, DST)                                                        \
      {                                                                       \
        _Pragma("unroll")                                                     \
        for (int j = 0; j < 3; ++j)                                           \
          DST[j] = *(const int4*)(bsp[j] + bsrc[j] + (K0));                   \
      }
#define WRITEAB(PA, PB)                                                       \
      {                                                                       \
        *(int4*)(&sm.u.mm.Hs[0][a_row][a_koct * 8]) = PA[0];                  \
        *(int4*)(&sm.u.mm.Hs[1][a_row][a_koct * 8]) = PA[1];                  \
        _Pragma("unroll")                                                     \
        for (int j = 0; j < 3; ++j)                                           \
          *(int4*)(&sm.u.mm.Bs[blev[j]][brow[j]][bkoct[j] * 8]) = PB[j];      \
      }
#define COMPUTE()                                                             \
      {                                                                       \
        bf16x8 ah[2], al[2], bh[3], bl[3];                                    \
        _Pragma("unroll")                                                     \
        for (int mf = 0; mf < 2; ++mf) {                                      \
          int row = wm + mf * 16 + lr;                                        \
          ah[mf] = *(const bf16x8*)(&sm.u.mm.Hs[0][row][lk * 8]);             \
          al[mf] = *(const bf16x8*)(&sm.u.mm.Hs[1][row][lk * 8]);             \
        }                                                                     \
        _Pragma("unroll")                                                     \
        for (int g = 0; g < 3; ++g) {                                         \
          int row = g * 32 + wi * 16 + lr;                                    \
          bh[g] = *(const bf16x8*)(&sm.u.mm.Bs[0][row][lk * 8]);              \
          bl[g] = *(const bf16x8*)(&sm.u.mm.Bs[1][row][lk * 8]);              \
        }                                                                     \
        _Pragma("unroll")                                                     \
        for (int mf = 0; mf < 2; ++mf)                                        \
          _Pragma("unroll")                                                   \
          for (int g = 0; g < 3; ++g) {                                       \
            acc[mf][g] = __builtin_amdgcn_mfma_f32_16x16x32_bf16(ah[mf], bh[g], acc[mf][g], 0, 0, 0); \
            acc[mf][g] = __builtin_amdgcn_mfma_f32_16x16x32_bf16(ah[mf], bl[g], acc[mf][g], 0, 0, 0); \
            acc[mf][g] = __builtin_amdgcn_mfma_f32_16x16x32_bf16(al[mf], bh[g], acc[mf][g], 0, 0, 0); \
          }                                                                   \
      }

      LOADA(0, paA); LOADB(0, pbA);
      LOADA(32, paB); LOADB(32, pbB);
      for (int k0 = 0; k0 < H_; k0 += 64) {
        __syncthreads();
        WRITEAB(paA, pbA);
        if (k0 + 64 < H_) { LOADA(k0 + 64, paA); LOADB(k0 + 64, pbA); }
        __syncthreads();
        COMPUTE();
        __syncthreads();
        WRITEAB(paB, pbB);
        if (k0 + 96 < H_) { LOADA(k0 + 96, paB); LOADB(k0 + 96, pbB); }
        __syncthreads();
        COMPUTE();
      }
#undef LOADA
#undef LOADB
#undef WRITEAB
#undef COMPUTE
      // fused gating epilogue: lane holds r/z/n for (t, i)
      int i = i0 + wi * 16 + lr;
#pragma unroll
      for (int mf = 0; mf < 2; ++mf)
#pragma unroll
        for (int r = 0; r < 4; ++r) {
          int slot = wm + mf * 16 + lk * 4 + r;
          int t = sm.tl[slot];
          if (t <= 0) continue;
          size_t pidx = (size_t)(t - 1) * H_ + i;
          float hin = bf2f(st_h[pidx]) + bf2f(st_l[pidx]);
          float ir = ig[(size_t)t * H3_ + i];
          float iz = ig[(size_t)t * H3_ + H_ + i];
          float in_ = ig[(size_t)t * H3_ + 2 * H_ + i];
          float rr = sigmoidf_(ir + acc[mf][0][r]);
          float uu = sigmoidf_(iz + acc[mf][1][r]);
          float nn = tanhf(in_ + rr * (acc[mf][2][r] + gbn[i]));
          float v = nn + uu * (hin - nn);
          ushort hb = f2bf(v);
          st_h[(size_t)t * H_ + i] = hb;
          st_l[(size_t)t * H_ + i] = f2bf(v - bf2f(hb));
        }
    }
    grid.sync();
  }
}

__global__ void k_final(const ushort* __restrict__ st_h,
                        const ushort* __restrict__ st_l,
                        float* __restrict__ out) {
  int i = blockIdx.x * 256 + threadIdx.x;
  if (i < H_)
    out[T_ * ACT_ + i] = bf2f(st_h[(size_t)(T_ - 1) * H_ + i]) +
                         bf2f(st_l[(size_t)(T_ - 1) * H_ + i]);
}

// ---------------------------------------------------------------------------
extern "C" void kernel_launch(void* const* d_in, const int* in_sizes, int n_in,
                              void* d_out, int out_size, void* d_ws, size_t ws_size,
                              hipStream_t stream) {
  const float* x      = (const float*)d_in[0];
  const float* state0 = (const float*)d_in[1];
  const int*   start  = (const int*)d_in[2];
  const float* pre_wm = (const float*)d_in[4];
  const float* pre_ws = (const float*)d_in[5];
  const float* pre_bm = (const float*)d_in[6];
  const float* pre_bs = (const float*)d_in[7];
  const float* gru_wih = (const float*)d_in[8];
  const float* gru_whh = (const float*)d_in[9];
  const float* gru_b  = (const float*)d_in[10];
  const float* gru_bn = (const float*)d_in[11];
  const float* p1_wm = (const float*)d_in[12];
  const float* p1_ws = (const float*)d_in[13];
  const float* p1_bm = (const float*)d_in[14];
  const float* p1_bs = (const float*)d_in[15];
  const float* p2_wm = (const float*)d_in[16];
  const float* p2_ws = (const float*)d_in[17];
  const float* p2_bm = (const float*)d_in[18];
  const float* p2_bs = (const float*)d_in[19];
  const float* p3_wm = (const float*)d_in[20];
  const float* p3_ws = (const float*)d_in[21];
  const float* p3_bm = (const float*)d_in[22];
  const float* p3_bs = (const float*)d_in[23];

  // ---- workspace bump allocator ----
  char* p = (char*)d_ws;
  auto nxt = [&](size_t bytes) { char* r = p; p += (bytes + 255) & ~255ul; return r; };
  ushort* wihh = (ushort*)nxt((size_t)H3_ * MLP_ * 2);   // wih hi -> (after ig GEMM) whh hi
  ushort* wihl = (ushort*)nxt((size_t)H3_ * MLP_ * 2);   // wih lo -> whh lo
  ushort* preWh = (ushort*)nxt((size_t)MLP_ * OBS_ * 2);
  ushort* preWl = (ushort*)nxt((size_t)MLP_ * OBS_ * 2);
  ushort* p1Wh = (ushort*)nxt((size_t)MLP_ * H_ * 2);
  ushort* p1Wl = (ushort*)nxt((size_t)MLP_ * H_ * 2);
  ushort* p2Wh = (ushort*)nxt((size_t)MLP_ * MLP_ * 2);
  ushort* p2Wl = (ushort*)nxt((size_t)MLP_ * MLP_ * 2);
  ushort* p3Wh = (ushort*)nxt((size_t)128 * MLP_ * 2);
  ushort* p3Wl = (ushort*)nxt((size_t)128 * MLP_ * 2);
  float* preB = (float*)nxt(MLP_ * 4);
  float* p1B  = (float*)nxt(MLP_ * 4);
  float* p2B  = (float*)nxt(MLP_ * 4);
  float* p3B  = (float*)nxt(ACT_ * 4);
  ushort* B1h = (ushort*)nxt((size_t)T_ * MLP_ * 2);
  ushort* B1l = (ushort*)nxt((size_t)T_ * MLP_ * 2);
  ushort* B2h = (ushort*)nxt((size_t)T_ * MLP_ * 2);  // x-split -> states hi -> y2 hi
  ushort* B2l = (ushort*)nxt((size_t)T_ * MLP_ * 2);
  float* igb = (float*)nxt((size_t)T_ * H3_ * 4);
  float* hg0 = (float*)nxt(H3_ * 4);
  int* counts  = (int*)nxt(2048 * 4);
  int* cursors = (int*)nxt(2048 * 4);
  int* li      = (int*)nxt(2048 * 4);
  int* offsets = (int*)nxt(2048 * 4);
  int* list    = (int*)nxt(2048 * 4);

  // ---- host: 8 noise keys (split(key(7), 8), partitionable) ----
  uint32_t nk0[8], nk1[8];
  for (int i = 0; i < 8; ++i) {
    uint32_t b1, b2;
    tf2x32(0u, 7u, 0u, (uint32_t)i, b1, b2);
    nk0[i] = b1; nk1[i] = b2;
  }

  NoiseArgs na;
  const float* wms[8] = {pre_wm, pre_bm, p1_wm, p1_bm, p2_wm, p2_bm, p3_wm, p3_bm};
  const float* wss[8] = {pre_ws, pre_bs, p1_ws, p1_bs, p2_ws, p2_bs, p3_ws, p3_bs};
  ushort* dhs[8] = {preWh, nullptr, p1Wh, nullptr, p2Wh, nullptr, p3Wh, nullptr};
  ushort* dls[8] = {preWl, nullptr, p1Wl, nullptr, p2Wl, nullptr, p3Wl, nullptr};
  float* dfs[8]  = {nullptr, preB, nullptr, p1B, nullptr, p2B, nullptr, p3B};
  uint32_t ns[8] = {MLP_ * OBS_, MLP_, MLP_ * H_, MLP_, MLP_ * MLP_, MLP_, ACT_ * MLP_, ACT_};
  uint32_t base = 0;
  for (int i = 0; i < 8; ++i) {
    na.d[i].wm = wms[i]; na.d[i].ws = wss[i];
    na.d[i].dh = dhs[i]; na.d[i].dl = dls[i]; na.d[i].df = dfs[i];
    na.d[i].k0 = nk0[i]; na.d[i].k1 = nk1[i];
    na.d[i].base = base; na.d[i].mode = (i & 1) ? 0u : 1u;
    base += ns[i];
  }
  na.total = base;
  na.meta_zero = counts;  // counts + cursors contiguous: 4096 ints

  dim3 b256(256);

  hipMemsetAsync(p3Wh + 16 * MLP_, 0, (size_t)112 * MLP_ * 2, stream);
  hipMemsetAsync(p3Wl + 16 * MLP_, 0, (size_t)112 * MLP_ * 2, stream);

  k_gen_noise<<<dim3(4096), b256, 0, stream>>>(na);
  k_split<<<dim3((H3_ * MLP_ / 4) / 256), b256, 0, stream>>>(gru_wih, wihh, wihl, H3_ * MLP_ / 4);
  k_split<<<dim3((T_ * OBS_ / 4) / 256), b256, 0, stream>>>(x, B2h, B2l, T_ * OBS_ / 4);

  // pre: z = mish(x @ preW^T + preB) -> B1 hi/lo
  k_mgemm<1, 1><<<dim3(MLP_ / 128, T_ / 128), b256, 0, stream>>>(
      B2h, B2l, preWh, preWl, preB, nullptr, B1h, B1l, OBS_, MLP_, MLP_);
  // igates = z @ wih^T + gru_b -> fp32
  k_mgemm<0, 0><<<dim3(H3_ / 128, T_ / 128), b256, 0, stream>>>(
      B1h, B1l, wihh, wihl, gru_b, igb, nullptr, nullptr, MLP_, H3_, H3_);

  // wih buffers now dead -> reuse for whh hi/lo split (stream-ordered)
  k_split<<<dim3((H3_ * H_ / 4) / 256), b256, 0, stream>>>(gru_whh, wihh, wihl, H3_ * H_ / 4);

  // cooperative fused scan (writes states hi/lo into B2h/B2l)
  {
    int maxb = 0;
    if (hipOccupancyMaxActiveBlocksPerMultiprocessor(&maxb, (const void*)k_scan, 256, 0)
            != hipSuccess || maxb < 1)
      maxb = 1;
    if (maxb > 4) maxb = 4;
    const float* a0 = igb; const float* a1 = gru_whh;
    const ushort* a2 = wihh; const ushort* a3 = wihl;
    const float* a4 = gru_bn; const float* a5 = state0; const int* a6 = start;
    int* a7 = counts; int* a8 = cursors; int* a9 = li; int* a10 = offsets; int* a11 = list;
    ushort* a12 = B2h; ushort* a13 = B2l; float* a14 = hg0;
    void* args[] = {&a0, &a1, &a2, &a3, &a4, &a5, &a6, &a7, &a8, &a9,
                    &a10, &a11, &a12, &a13, &a14};
    hipLaunchCooperativeKernel((void*)k_scan, dim3(256 * maxb), dim3(256), args, 0, stream);
  }

  // final_state output (before p2 overwrites B2)
  k_final<<<dim3(4), b256, 0, stream>>>(B2h, B2l, (float*)d_out);

  // post MLP
  k_mgemm<1, 1><<<dim3(MLP_ / 128, T_ / 128), b256, 0, stream>>>(
      B2h, B2l, p1Wh, p1Wl, p1B, nullptr, B1h, B1l, H_, MLP_, MLP_);
  k_mgemm<1, 1><<<dim3(MLP_ / 128, T_ / 128), b256, 0, stream>>>(
      B1h, B1l, p2Wh, p2Wl, p2B, nullptr, B2h, B2l, MLP_, MLP_, MLP_);
  k_mgemm<0, 0><<<dim3(1, T_ / 128), b256, 0, stream>>>(
      B2h, B2l, p3Wh, p3Wl, p3B, (float*)d_out, nullptr, nullptr, MLP_, ACT_, ACT_);
}

// Round 8
// 996.006 us; speedup vs baseline: 1.6148x; 1.6148x over previous
//
#include <hip/hip_runtime.h>
#include <cstdint>
#include <cstddef>

#define T_ 2048
#define OBS_ 512
#define MLP_ 1024
#define H_ 1024
#define ACT_ 16
#define H3_ 3072
#define NROUNDS 20

typedef short bf16x8 __attribute__((ext_vector_type(8)));
typedef float f32x4 __attribute__((ext_vector_type(4)));

// ---------------------------------------------------------------------------
// threefry2x32 (JAX/XLA exact)
// ---------------------------------------------------------------------------
__host__ __device__ __forceinline__ uint32_t rotl32(uint32_t v, int d) {
  return (v << d) | (v >> (32 - d));
}
__host__ __device__ __forceinline__ void tf2x32(uint32_t k0, uint32_t k1,
                                                uint32_t x0, uint32_t x1,
                                                uint32_t& o0, uint32_t& o1) {
  uint32_t ks2 = k0 ^ k1 ^ 0x1BD11BDAu;
  x0 += k0; x1 += k1;
  x0 += x1; x1 = rotl32(x1, 13); x1 ^= x0;
  x0 += x1; x1 = rotl32(x1, 15); x1 ^= x0;
  x0 += x1; x1 = rotl32(x1, 26); x1 ^= x0;
  x0 += x1; x1 = rotl32(x1, 6);  x1 ^= x0;
  x0 += k1; x1 += ks2 + 1u;
  x0 += x1; x1 = rotl32(x1, 17); x1 ^= x0;
  x0 += x1; x1 = rotl32(x1, 29); x1 ^= x0;
  x0 += x1; x1 = rotl32(x1, 16); x1 ^= x0;
  x0 += x1; x1 = rotl32(x1, 24); x1 ^= x0;
  x0 += ks2; x1 += k0 + 2u;
  x0 += x1; x1 = rotl32(x1, 13); x1 ^= x0;
  x0 += x1; x1 = rotl32(x1, 15); x1 ^= x0;
  x0 += x1; x1 = rotl32(x1, 26); x1 ^= x0;
  x0 += x1; x1 = rotl32(x1, 6);  x1 ^= x0;
  x0 += k0; x1 += k1 + 3u;
  x0 += x1; x1 = rotl32(x1, 17); x1 ^= x0;
  x0 += x1; x1 = rotl32(x1, 29); x1 ^= x0;
  x0 += x1; x1 = rotl32(x1, 16); x1 ^= x0;
  x0 += x1; x1 = rotl32(x1, 24); x1 ^= x0;
  x0 += k1; x1 += ks2 + 4u;
  x0 += x1; x1 = rotl32(x1, 13); x1 ^= x0;
  x0 += x1; x1 = rotl32(x1, 15); x1 ^= x0;
  x0 += x1; x1 = rotl32(x1, 26); x1 ^= x0;
  x0 += x1; x1 = rotl32(x1, 6);  x1 ^= x0;
  x0 += ks2; x1 += k0 + 5u;
  o0 = x0; o1 = x1;
}

// XLA ErfInv32 (Giles)
__device__ __forceinline__ float erfinv_f32(float x) {
  float w = -log1pf(-x * x);
  float p;
  if (w < 5.0f) {
    w = w - 2.5f;
    p = 2.81022636e-08f;
    p = fmaf(p, w, 3.43273939e-07f);
    p = fmaf(p, w, -3.5233877e-06f);
    p = fmaf(p, w, -4.39150654e-06f);
    p = fmaf(p, w, 0.00021858087f);
    p = fmaf(p, w, -0.00125372503f);
    p = fmaf(p, w, -0.00417768164f);
    p = fmaf(p, w, 0.246640727f);
    p = fmaf(p, w, 1.50140941f);
  } else {
    w = sqrtf(w) - 3.0f;
    p = -0.000200214257f;
    p = fmaf(p, w, 0.000100950558f);
    p = fmaf(p, w, 0.00134934322f);
    p = fmaf(p, w, -0.00367342844f);
    p = fmaf(p, w, 0.00573950773f);
    p = fmaf(p, w, -0.0076224613f);
    p = fmaf(p, w, 0.00943887047f);
    p = fmaf(p, w, 1.00167406f);
    p = fmaf(p, w, 2.83297682f);
  }
  return p * x;
}

__device__ __forceinline__ float bits_to_normal(uint32_t bits) {
  const float lo = -0.99999994f;
  float f = __uint_as_float((bits >> 9) | 0x3f800000u) - 1.0f;
  float u = fmaf(f, 2.0f, lo);
  u = fmaxf(lo, u);
  return 1.41421356237f * erfinv_f32(u);
}

__device__ __forceinline__ float sigmoidf_(float x) {
  return 1.0f / (1.0f + expf(-x));
}
__device__ __forceinline__ float mishf_(float x) {
  float sp = fmaxf(x, 0.0f) + log1pf(expf(-fabsf(x)));
  return x * tanhf(sp);
}

// bf16 RNE split helpers
__device__ __forceinline__ ushort f2bf(float v) {
  uint32_t u = __float_as_uint(v);
  uint32_t r = (u + 0x7FFFu + ((u >> 16) & 1u)) >> 16;
  return (ushort)r;
}
__device__ __forceinline__ float bf2f(ushort b) {
  return __uint_as_float(((uint32_t)b) << 16);
}

// ---------------------------------------------------------------------------
// Noise: v = wm + ws*normal; weights -> hi/lo bf16, biases -> fp32.
// Also zeroes meta (counts+cursors, 4096 ints) in first 16 blocks.
// ---------------------------------------------------------------------------
struct NoiseDesc {
  const float* wm; const float* ws;
  ushort* dh; ushort* dl; float* df;
  uint32_t k0, k1, base, mode;
};
struct NoiseArgs { NoiseDesc d[8]; uint32_t total; int* meta_zero; };

__global__ __launch_bounds__(256) void k_gen_noise(NoiseArgs a) {
  if (blockIdx.x < 16) a.meta_zero[blockIdx.x * 256 + threadIdx.x] = 0;
  uint32_t idx = blockIdx.x * 256u + threadIdx.x;
  for (; idx < a.total; idx += gridDim.x * 256u) {
    int ti = 0;
#pragma unroll
    for (int i = 1; i < 8; ++i) if (idx >= a.d[i].base) ti = i;
    NoiseDesc dd = a.d[ti];
    uint32_t j = idx - dd.base;
    uint32_t b1, b2;
    tf2x32(dd.k0, dd.k1, 0u, j, b1, b2);
    float v = fmaf(dd.ws[j], bits_to_normal(b1 ^ b2), dd.wm[j]);
    if (dd.mode) {
      ushort hb = f2bf(v);
      dd.dh[j] = hb;
      dd.dl[j] = f2bf(v - bf2f(hb));
    } else {
      dd.df[j] = v;
    }
  }
}

// fp32 -> (hi, lo) bf16 split, vectorized
__global__ __launch_bounds__(256) void k_split(const float* __restrict__ in,
                                               ushort* __restrict__ h,
                                               ushort* __restrict__ l, int n4) {
  int i = blockIdx.x * 256 + threadIdx.x;
  if (i >= n4) return;
  float4 v = ((const float4*)in)[i];
  ushort4 hb, lb;
  hb.x = f2bf(v.x); lb.x = f2bf(v.x - bf2f(hb.x));
  hb.y = f2bf(v.y); lb.y = f2bf(v.y - bf2f(hb.y));
  hb.z = f2bf(v.z); lb.z = f2bf(v.z - bf2f(hb.z));
  hb.w = f2bf(v.w); lb.w = f2bf(v.w - bf2f(hb.w));
  ((ushort4*)h)[i] = hb;
  ((ushort4*)l)[i] = lb;
}

// ---------------------------------------------------------------------------
// MFMA split-bf16 GEMM (feed-forward; unchanged — verified r3/r4/r5).
// ---------------------------------------------------------------------------
template <int ACTF, int OUTM>
__global__ __launch_bounds__(256, 2) void k_mgemm(
    const ushort* __restrict__ Ah, const ushort* __restrict__ Al,
    const ushort* __restrict__ Wh, const ushort* __restrict__ Wl,
    const float* __restrict__ bias,
    float* __restrict__ Cf, ushort* __restrict__ Ch, ushort* __restrict__ Cl,
    int K, int Nreal, int ldc) {
  __shared__ ushort sA[2][128 * 32];
  __shared__ ushort sW[2][128 * 32];
  const int tid = threadIdx.x;
  const int m0 = blockIdx.y * 128, n0 = blockIdx.x * 128;
  const int wid = tid >> 6, lane = tid & 63;
  const int wm = (wid >> 1) * 64, wn = (wid & 1) * 64;
  const int lr = lane & 15, lk = lane >> 4;
  const int r0 = tid >> 2;
  const int c0 = (tid & 3) * 8;
  f32x4 acc[4][4] = {};
  for (int k0 = 0; k0 < K; k0 += 32) {
    const size_t aoff0 = (size_t)(m0 + r0) * K + k0 + c0;
    const size_t aoff1 = (size_t)(m0 + r0 + 64) * K + k0 + c0;
    const size_t woff0 = (size_t)(n0 + r0) * K + k0 + c0;
    const size_t woff1 = (size_t)(n0 + r0 + 64) * K + k0 + c0;
    int4 ah0 = *(const int4*)(Ah + aoff0);
    int4 ah1 = *(const int4*)(Ah + aoff1);
    int4 al0 = *(const int4*)(Al + aoff0);
    int4 al1 = *(const int4*)(Al + aoff1);
    int4 wh0 = *(const int4*)(Wh + woff0);
    int4 wh1 = *(const int4*)(Wh + woff1);
    int4 wl0 = *(const int4*)(Wl + woff0);
    int4 wl1 = *(const int4*)(Wl + woff1);
    __syncthreads();
    *(int4*)(&sA[0][r0 * 32 + c0]) = ah0;
    *(int4*)(&sA[0][(r0 + 64) * 32 + c0]) = ah1;
    *(int4*)(&sA[1][r0 * 32 + c0]) = al0;
    *(int4*)(&sA[1][(r0 + 64) * 32 + c0]) = al1;
    *(int4*)(&sW[0][r0 * 32 + c0]) = wh0;
    *(int4*)(&sW[0][(r0 + 64) * 32 + c0]) = wh1;
    *(int4*)(&sW[1][r0 * 32 + c0]) = wl0;
    *(int4*)(&sW[1][(r0 + 64) * 32 + c0]) = wl1;
    __syncthreads();
    bf16x8 fah[4], fal[4], fwh[4], fwl[4];
#pragma unroll
    for (int f = 0; f < 4; ++f) {
      int ar = (wm + f * 16 + lr) * 32 + lk * 8;
      fah[f] = *(const bf16x8*)(&sA[0][ar]);
      fal[f] = *(const bf16x8*)(&sA[1][ar]);
      int wr = (wn + f * 16 + lr) * 32 + lk * 8;
      fwh[f] = *(const bf16x8*)(&sW[0][wr]);
      fwl[f] = *(const bf16x8*)(&sW[1][wr]);
    }
#pragma unroll
    for (int mf = 0; mf < 4; ++mf)
#pragma unroll
      for (int nf = 0; nf < 4; ++nf) {
        acc[mf][nf] = __builtin_amdgcn_mfma_f32_16x16x32_bf16(fah[mf], fwh[nf], acc[mf][nf], 0, 0, 0);
        acc[mf][nf] = __builtin_amdgcn_mfma_f32_16x16x32_bf16(fah[mf], fwl[nf], acc[mf][nf], 0, 0, 0);
        acc[mf][nf] = __builtin_amdgcn_mfma_f32_16x16x32_bf16(fal[mf], fwh[nf], acc[mf][nf], 0, 0, 0);
      }
  }
#pragma unroll
  for (int mf = 0; mf < 4; ++mf)
#pragma unroll
    for (int nf = 0; nf < 4; ++nf) {
      int col = n0 + wn + nf * 16 + lr;
      if (col >= Nreal) continue;
      float bv = bias[col];
#pragma unroll
      for (int r = 0; r < 4; ++r) {
        int row = m0 + wm + mf * 16 + lk * 4 + r;
        float v = acc[mf][nf][r] + bv;
        if (ACTF) v = mishf_(v);
        if (OUTM == 0) {
          Cf[(size_t)row * ldc + col] = v;
        } else {
          ushort hb = f2bf(v);
          Ch[(size_t)row * ldc + col] = hb;
          Cl[(size_t)row * ldc + col] = f2bf(v - bf2f(hb));
        }
      }
    }
}

// ---------------------------------------------------------------------------
// Segment-scan metadata (separate small kernels; verified round 1)
// ---------------------------------------------------------------------------
__global__ void k_li(const int* __restrict__ start, int* __restrict__ li,
                     int* __restrict__ counts) {
  int t = blockIdx.x * 256 + threadIdx.x;
  if (t >= T_) return;
  int l = 0, tt = t;
  while (tt > 0 && start[tt] == 0) { tt--; l++; }
  li[t] = l;
  if (t > 0) atomicAdd(&counts[l], 1);
}

__global__ __launch_bounds__(256) void k_offsets(const int* __restrict__ counts,
                                                 int* __restrict__ offsets) {
  __shared__ int a[2048], b[2048];
  int tid = threadIdx.x;
  for (int i = tid; i < 2048; i += 256) a[i] = counts[i];
  __syncthreads();
  int* cur = a; int* nxt = b;
  for (int d = 1; d < 2048; d <<= 1) {
    for (int i = tid; i < 2048; i += 256)
      nxt[i] = cur[i] + (i >= d ? cur[i - d] : 0);
    __syncthreads();
    int* t_ = cur; cur = nxt; nxt = t_;
  }
  for (int i = tid; i < 2048; i += 256)
    offsets[i] = (i == 0) ? 0 : cur[i - 1];
}

__global__ void k_scatter(const int* __restrict__ li, const int* __restrict__ offsets,
                          int* __restrict__ cursors, int* __restrict__ list) {
  int t = blockIdx.x * 256 + threadIdx.x;
  if (t <= 0 || t >= T_) return;
  int l = li[t];
  int pos = atomicAdd(&cursors[l], 1);
  list[offsets[l] + pos] = t;
}

// hg0 = (state0*keep0) @ whh^T  (grid 256: 4 waves x 3 rows per block)
__global__ __launch_bounds__(256) void k_hg0(
    const float* __restrict__ whhf, const float* __restrict__ state0,
    const int* __restrict__ start, float* __restrict__ hg0) {
  const float keep0 = 1.0f - (float)start[0];
  int gw = blockIdx.x * 4 + (threadIdx.x >> 6);
  int lane = threadIdx.x & 63;
  for (int r = gw * 3; r < gw * 3 + 3 && r < H3_; ++r) {
    const float* wr = whhf + (size_t)r * H_;
    float s = 0.f;
    for (int c = lane; c < H_; c += 64) s = fmaf(wr[c], state0[c] * keep0, s);
    for (int o = 32; o; o >>= 1) s += __shfl_down(s, o, 64);
    if (lane == 0) hg0[r] = s;
  }
}

// round 0 gating: all segment starts + t=0
__global__ __launch_bounds__(256) void k_gate0(
    const float* __restrict__ ig, const float* __restrict__ gbn,
    const float* __restrict__ state0, const int* __restrict__ start,
    const int* __restrict__ counts, const int* __restrict__ offsets,
    const int* __restrict__ list, const float* __restrict__ hg0,
    ushort* __restrict__ st_h, ushort* __restrict__ st_l) {
  const float keep0 = 1.0f - (float)start[0];
  int cnt0 = counts[0], off0 = offsets[0];
  int total = (cnt0 + 1) * H_;
  for (int e = blockIdx.x * 256 + threadIdx.x; e < total; e += gridDim.x * 256) {
    int s = e >> 10, i = e & (H_ - 1);
    int t; float hin, hr, hz, hn;
    if (s == 0) {
      t = 0; hin = state0[i] * keep0;
      hr = hg0[i]; hz = hg0[H_ + i]; hn = hg0[2 * H_ + i];
    } else {
      t = list[off0 + s - 1]; hin = 0.f; hr = 0.f; hz = 0.f; hn = 0.f;
    }
    float ir = ig[(size_t)t * H3_ + i];
    float iz = ig[(size_t)t * H3_ + H_ + i];
    float in_ = ig[(size_t)t * H3_ + 2 * H_ + i];
    float r = sigmoidf_(ir + hr), u = sigmoidf_(iz + hz);
    float n = tanhf(in_ + r * (hn + gbn[i]));
    float v = n + u * (hin - n);
    ushort hb = f2bf(v);
    st_h[(size_t)t * H_ + i] = hb;
    st_l[(size_t)t * H_ + i] = f2bf(v - bf2f(hb));
  }
}

// ---------------------------------------------------------------------------
// One scan round (k >= 1): MFMA GEMM tiles 64t x 32i (x3 gates) with fused
// gating epilogue. Tile body lifted verbatim from round-5 k_scan P6 (verified).
// ---------------------------------------------------------------------------
struct SMemRound {
  ushort Hs[2][64][40];   // [hi/lo][t-slot][k], row stride 80B (2-way free)
  ushort Bs[2][96][40];   // [hi/lo][g*32+ii][k]
  int tl[64];
};

__global__ __launch_bounds__(256) void k_round(
    const int k, const float* __restrict__ ig,
    const ushort* __restrict__ whh_h, const ushort* __restrict__ whh_l,
    const float* __restrict__ gbn,
    const int* __restrict__ counts, const int* __restrict__ offsets,
    const int* __restrict__ list,
    ushort* __restrict__ st_h, ushort* __restrict__ st_l) {
  const int cnt = counts[k];
  if (cnt == 0) return;
  __shared__ SMemRound sm;
  const int tid = threadIdx.x, bid = blockIdx.x, nb = gridDim.x;
  const int off = offsets[k];
  const int mtiles = (cnt + 63) >> 6;
  const int tiles = mtiles << 5;   // x32 i-tiles of 32 i's

  const int wid = tid >> 6, lane = tid & 63;
  const int lr = lane & 15, lk = lane >> 4;
  const int wm = (wid >> 1) * 32;  // m-half: 0 or 32
  const int wi = wid & 1;          // i-half within 32-i tile

  // staging cell decode (thread-invariant)
  const int a_koct = tid & 3, a_row = (tid >> 2) & 63;
  int blev[3], brow[3], bkoct[3];
#pragma unroll
  for (int j = 0; j < 3; ++j) {
    int c = tid + 256 * j;          // 0..767: lev*384 + row*4 + koct
    blev[j] = c / 384;
    int rem = c - blev[j] * 384;
    brow[j] = rem >> 2;
    bkoct[j] = rem & 3;
  }
  const ushort* bsp[3];
#pragma unroll
  for (int j = 0; j < 3; ++j) bsp[j] = blev[j] ? whh_l : whh_h;

  for (int tile = bid; tile < tiles; tile += nb) {
    int mt = tile >> 5;
    int i0 = (tile & 31) << 5;
    __syncthreads();
    if (tid < 64) {
      int s = mt * 64 + tid;
      sm.tl[tid] = (s < cnt) ? list[off + s] : 0;  // 0 = invalid slot
    }
    __syncthreads();

    size_t bsrc[3];
#pragma unroll
    for (int j = 0; j < 3; ++j)
      bsrc[j] = (size_t)((brow[j] >> 5) * H_ + i0 + (brow[j] & 31)) * H_ + bkoct[j] * 8;

    f32x4 acc[2][3] = {};
    int4 paA[2], paB[2], pbA[3], pbB[3];

#define LOADA(K0, DST)                                                        \
    {                                                                         \
      int t0_ = sm.tl[a_row];                                                 \
      DST[0] = make_int4(0, 0, 0, 0); DST[1] = make_int4(0, 0, 0, 0);         \
      if (t0_ > 0) {                                                          \
        size_t base_ = (size_t)(t0_ - 1) * H_ + (K0) + a_koct * 8;            \
        DST[0] = *(const int4*)(st_h + base_);                                \
        DST[1] = *(const int4*)(st_l + base_);                                \
      }                                                                       \
    }
#define LOADB(K0, DST)                                                        \
    {                                                                         \
      _Pragma("unroll")                                                       \
      for (int j = 0; j < 3; ++j)                                             \
        DST[j] = *(const int4*)(bsp[j] + bsrc[j] + (K0));                     \
    }
#define WRITEAB(PA, PB)                                                       \
    {                                                                         \
      *(int4*)(&sm.Hs[0][a_row][a_koct * 8]) = PA[0];                         \
      *(int4*)(&sm.Hs[1][a_row][a_koct * 8]) = PA[1];                         \
      _Pragma("unroll")                                                       \
      for (int j = 0; j < 3; ++j)                                             \
        *(int4*)(&sm.Bs[blev[j]][brow[j]][bkoct[j] * 8]) = PB[j];             \
    }
#define COMPUTE()                                                             \
    {                                                                         \
      bf16x8 ah[2], al[2], bh[3], bl[3];                                      \
      _Pragma("unroll")                                                       \
      for (int mf = 0; mf < 2; ++mf) {                                        \
        int row = wm + mf * 16 + lr;                                          \
        ah[mf] = *(const bf16x8*)(&sm.Hs[0][row][lk * 8]);                    \
        al[mf] = *(const bf16x8*)(&sm.Hs[1][row][lk * 8]);                    \
      }                                                                       \
      _Pragma("unroll")                                                       \
      for (int g = 0; g < 3; ++g) {                                           \
        int row = g * 32 + wi * 16 + lr;                                      \
        bh[g] = *(const bf16x8*)(&sm.Bs[0][row][lk * 8]);                     \
        bl[g] = *(const bf16x8*)(&sm.Bs[1][row][lk * 8]);                     \
      }                                                                       \
      _Pragma("unroll")                                                       \
      for (int mf = 0; mf < 2; ++mf)                                          \
        _Pragma("unroll")                                                     \
        for (int g = 0; g < 3; ++g) {                                         \
          acc[mf][g] = __builtin_amdgcn_mfma_f32_16x16x32_bf16(ah[mf], bh[g], acc[mf][g], 0, 0, 0); \
          acc[mf][g] = __builtin_amdgcn_mfma_f32_16x16x32_bf16(ah[mf], bl[g], acc[mf][g], 0, 0, 0); \
          acc[mf][g] = __builtin_amdgcn_mfma_f32_16x16x32_bf16(al[mf], bh[g], acc[mf][g], 0, 0, 0); \
        }                                                                     \
    }

    LOADA(0, paA); LOADB(0, pbA);
    LOADA(32, paB); LOADB(32, pbB);
    for (int k0 = 0; k0 < H_; k0 += 64) {
      __syncthreads();
      WRITEAB(paA, pbA);
      if (k0 + 64 < H_) { LOADA(k0 + 64, paA); LOADB(k0 + 64, pbA); }
      __syncthreads();
      COMPUTE();
      __syncthreads();
      WRITEAB(paB, pbB);
      if (k0 + 96 < H_) { LOADA(k0 + 96, paB); LOADB(k0 + 96, pbB); }
      __syncthreads();
      COMPUTE();
    }
#undef LOADA
#undef LOADB
#undef WRITEAB
#undef COMPUTE
    // fused gating epilogue: lane holds r/z/n for (t, i)
    int i = i0 + wi * 16 + lr;
#pragma unroll
    for (int mf = 0; mf < 2; ++mf)
#pragma unroll
      for (int r = 0; r < 4; ++r) {
        int slot = wm + mf * 16 + lk * 4 + r;
        int t = sm.tl[slot];
        if (t <= 0) continue;
        size_t pidx = (size_t)(t - 1) * H_ + i;
        float hin = bf2f(st_h[pidx]) + bf2f(st_l[pidx]);
        float ir = ig[(size_t)t * H3_ + i];
        float iz = ig[(size_t)t * H3_ + H_ + i];
        float in_ = ig[(size_t)t * H3_ + 2 * H_ + i];
        float rr = sigmoidf_(ir + acc[mf][0][r]);
        float uu = sigmoidf_(iz + acc[mf][1][r]);
        float nn = tanhf(in_ + rr * (acc[mf][2][r] + gbn[i]));
        float v = nn + uu * (hin - nn);
        ushort hb = f2bf(v);
        st_h[(size_t)t * H_ + i] = hb;
        st_l[(size_t)t * H_ + i] = f2bf(v - bf2f(hb));
      }
  }
}

// Sequential cleanup for rounds >= NROUNDS (vanishingly unlikely): 1 WG.
__global__ __launch_bounds__(256) void k_cleanup(
    const float* __restrict__ ig, const float* __restrict__ whhf,
    const float* __restrict__ gbn, const int* __restrict__ counts,
    const int* __restrict__ offsets, const int* __restrict__ list,
    ushort* __restrict__ st_h, ushort* __restrict__ st_l) {
  __shared__ float hbuf[H_];
  __shared__ float hg[H3_];
  const int tid = threadIdx.x;
  for (int k = NROUNDS; k < 2048; ++k) {
    int cnt = counts[k];
    if (cnt == 0) return;
    int off = offsets[k];
    for (int s = 0; s < cnt; ++s) {
      int t = list[off + s];
      for (int i = tid; i < H_; i += 256) {
        size_t p = (size_t)(t - 1) * H_ + i;
        hbuf[i] = bf2f(st_h[p]) + bf2f(st_l[p]);
      }
      __syncthreads();
      int wv = tid >> 6, ln = tid & 63;
      for (int r = wv; r < H3_; r += 4) {
        const float* wr = whhf + (size_t)r * H_;
        float sum = 0.f;
#pragma unroll 4
        for (int u = 0; u < 16; ++u) {
          int c = ln * 16 + u;
          sum = fmaf(wr[c], hbuf[c], sum);
        }
#pragma unroll
        for (int d = 32; d > 0; d >>= 1) sum += __shfl_down(sum, d, 64);
        if (ln == 0) hg[r] = sum;
      }
      __syncthreads();
      for (int i = tid; i < H_; i += 256) {
        float hin = hbuf[i];
        float r_ = sigmoidf_(ig[(size_t)t * H3_ + i] + hg[i]);
        float u_ = sigmoidf_(ig[(size_t)t * H3_ + H_ + i] + hg[H_ + i]);
        float n_ = tanhf(ig[(size_t)t * H3_ + 2 * H_ + i] + r_ * (hg[2 * H_ + i] + gbn[i]));
        float v = n_ + u_ * (hin - n_);
        ushort hb = f2bf(v);
        st_h[(size_t)t * H_ + i] = hb;
        st_l[(size_t)t * H_ + i] = f2bf(v - bf2f(hb));
      }
      __syncthreads();
    }
  }
}

__global__ void k_final(const ushort* __restrict__ st_h,
                        const ushort* __restrict__ st_l,
                        float* __restrict__ out) {
  int i = blockIdx.x * 256 + threadIdx.x;
  if (i < H_)
    out[T_ * ACT_ + i] = bf2f(st_h[(size_t)(T_ - 1) * H_ + i]) +
                         bf2f(st_l[(size_t)(T_ - 1) * H_ + i]);
}

// ---------------------------------------------------------------------------
extern "C" void kernel_launch(void* const* d_in, const int* in_sizes, int n_in,
                              void* d_out, int out_size, void* d_ws, size_t ws_size,
                              hipStream_t stream) {
  const float* x      = (const float*)d_in[0];
  const float* state0 = (const float*)d_in[1];
  const int*   start  = (const int*)d_in[2];
  const float* pre_wm = (const float*)d_in[4];
  const float* pre_ws = (const float*)d_in[5];
  const float* pre_bm = (const float*)d_in[6];
  const float* pre_bs = (const float*)d_in[7];
  const float* gru_wih = (const float*)d_in[8];
  const float* gru_whh = (const float*)d_in[9];
  const float* gru_b  = (const float*)d_in[10];
  const float* gru_bn = (const float*)d_in[11];
  const float* p1_wm = (const float*)d_in[12];
  const float* p1_ws = (const float*)d_in[13];
  const float* p1_bm = (const float*)d_in[14];
  const float* p1_bs = (const float*)d_in[15];
  const float* p2_wm = (const float*)d_in[16];
  const float* p2_ws = (const float*)d_in[17];
  const float* p2_bm = (const float*)d_in[18];
  const float* p2_bs = (const float*)d_in[19];
  const float* p3_wm = (const float*)d_in[20];
  const float* p3_ws = (const float*)d_in[21];
  const float* p3_bm = (const float*)d_in[22];
  const float* p3_bs = (const float*)d_in[23];

  // ---- workspace bump allocator ----
  char* p = (char*)d_ws;
  auto nxt = [&](size_t bytes) { char* r = p; p += (bytes + 255) & ~255ul; return r; };
  ushort* wihh = (ushort*)nxt((size_t)H3_ * MLP_ * 2);   // wih hi -> (after ig GEMM) whh hi
  ushort* wihl = (ushort*)nxt((size_t)H3_ * MLP_ * 2);   // wih lo -> whh lo
  ushort* preWh = (ushort*)nxt((size_t)MLP_ * OBS_ * 2);
  ushort* preWl = (ushort*)nxt((size_t)MLP_ * OBS_ * 2);
  ushort* p1Wh = (ushort*)nxt((size_t)MLP_ * H_ * 2);
  ushort* p1Wl = (ushort*)nxt((size_t)MLP_ * H_ * 2);
  ushort* p2Wh = (ushort*)nxt((size_t)MLP_ * MLP_ * 2);
  ushort* p2Wl = (ushort*)nxt((size_t)MLP_ * MLP_ * 2);
  ushort* p3Wh = (ushort*)nxt((size_t)128 * MLP_ * 2);
  ushort* p3Wl = (ushort*)nxt((size_t)128 * MLP_ * 2);
  float* preB = (float*)nxt(MLP_ * 4);
  float* p1B  = (float*)nxt(MLP_ * 4);
  float* p2B  = (float*)nxt(MLP_ * 4);
  float* p3B  = (float*)nxt(ACT_ * 4);
  ushort* B1h = (ushort*)nxt((size_t)T_ * MLP_ * 2);
  ushort* B1l = (ushort*)nxt((size_t)T_ * MLP_ * 2);
  ushort* B2h = (ushort*)nxt((size_t)T_ * MLP_ * 2);  // x-split -> states hi -> y2 hi
  ushort* B2l = (ushort*)nxt((size_t)T_ * MLP_ * 2);
  float* igb = (float*)nxt((size_t)T_ * H3_ * 4);
  float* hg0 = (float*)nxt(H3_ * 4);
  int* counts  = (int*)nxt(2048 * 4);
  int* cursors = (int*)nxt(2048 * 4);
  int* li      = (int*)nxt(2048 * 4);
  int* offsets = (int*)nxt(2048 * 4);
  int* list    = (int*)nxt(2048 * 4);

  // ---- host: 8 noise keys (split(key(7), 8), partitionable) ----
  uint32_t nk0[8], nk1[8];
  for (int i = 0; i < 8; ++i) {
    uint32_t b1, b2;
    tf2x32(0u, 7u, 0u, (uint32_t)i, b1, b2);
    nk0[i] = b1; nk1[i] = b2;
  }

  NoiseArgs na;
  const float* wms[8] = {pre_wm, pre_bm, p1_wm, p1_bm, p2_wm, p2_bm, p3_wm, p3_bm};
  const float* wss[8] = {pre_ws, pre_bs, p1_ws, p1_bs, p2_ws, p2_bs, p3_ws, p3_bs};
  ushort* dhs[8] = {preWh, nullptr, p1Wh, nullptr, p2Wh, nullptr, p3Wh, nullptr};
  ushort* dls[8] = {preWl, nullptr, p1Wl, nullptr, p2Wl, nullptr, p3Wl, nullptr};
  float* dfs[8]  = {nullptr, preB, nullptr, p1B, nullptr, p2B, nullptr, p3B};
  uint32_t ns[8] = {MLP_ * OBS_, MLP_, MLP_ * H_, MLP_, MLP_ * MLP_, MLP_, ACT_ * MLP_, ACT_};
  uint32_t base = 0;
  for (int i = 0; i < 8; ++i) {
    na.d[i].wm = wms[i]; na.d[i].ws = wss[i];
    na.d[i].dh = dhs[i]; na.d[i].dl = dls[i]; na.d[i].df = dfs[i];
    na.d[i].k0 = nk0[i]; na.d[i].k1 = nk1[i];
    na.d[i].base = base; na.d[i].mode = (i & 1) ? 0u : 1u;
    base += ns[i];
  }
  na.total = base;
  na.meta_zero = counts;  // counts + cursors contiguous: 4096 ints

  dim3 b256(256);

  hipMemsetAsync(p3Wh + 16 * MLP_, 0, (size_t)112 * MLP_ * 2, stream);
  hipMemsetAsync(p3Wl + 16 * MLP_, 0, (size_t)112 * MLP_ * 2, stream);

  k_gen_noise<<<dim3(4096), b256, 0, stream>>>(na);
  k_split<<<dim3((H3_ * MLP_ / 4) / 256), b256, 0, stream>>>(gru_wih, wihh, wihl, H3_ * MLP_ / 4);
  k_split<<<dim3((T_ * OBS_ / 4) / 256), b256, 0, stream>>>(x, B2h, B2l, T_ * OBS_ / 4);

  // metadata
  k_li<<<dim3(T_ / 256), b256, 0, stream>>>(start, li, counts);
  k_offsets<<<dim3(1), b256, 0, stream>>>(counts, offsets);
  k_scatter<<<dim3(T_ / 256), b256, 0, stream>>>(li, offsets, cursors, list);
  k_hg0<<<dim3(256), b256, 0, stream>>>(gru_whh, state0, start, hg0);

  // pre: z = mish(x @ preW^T + preB) -> B1 hi/lo
  k_mgemm<1, 1><<<dim3(MLP_ / 128, T_ / 128), b256, 0, stream>>>(
      B2h, B2l, preWh, preWl, preB, nullptr, B1h, B1l, OBS_, MLP_, MLP_);
  // igates = z @ wih^T + gru_b -> fp32
  k_mgemm<0, 0><<<dim3(H3_ / 128, T_ / 128), b256, 0, stream>>>(
      B1h, B1l, wihh, wihl, gru_b, igb, nullptr, nullptr, MLP_, H3_, H3_);

  // wih buffers dead -> reuse for whh hi/lo split
  k_split<<<dim3((H3_ * H_ / 4) / 256), b256, 0, stream>>>(gru_whh, wihh, wihl, H3_ * H_ / 4);

  // scan: round 0 + per-round MFMA kernels (no grid.sync)
  k_gate0<<<dim3(512), b256, 0, stream>>>(igb, gru_bn, state0, start, counts,
                                          offsets, list, hg0, B2h, B2l);
  for (int k = 1; k < NROUNDS; ++k)
    k_round<<<dim3(512), b256, 0, stream>>>(k, igb, wihh, wihl, gru_bn, counts,
                                            offsets, list, B2h, B2l);
  k_cleanup<<<dim3(1), b256, 0, stream>>>(igb, gru_whh, gru_bn, counts, offsets,
                                          list, B2h, B2l);

  // final_state output (before p2 overwrites B2)
  k_final<<<dim3(4), b256, 0, stream>>>(B2h, B2l, (float*)d_out);

  // post MLP
  k_mgemm<1, 1><<<dim3(MLP_ / 128, T_ / 128), b256, 0, stream>>>(
      B2h, B2l, p1Wh, p1Wl, p1B, nullptr, B1h, B1l, H_, MLP_, MLP_);
  k_mgemm<1, 1><<<dim3(MLP_ / 128, T_ / 128), b256, 0, stream>>>(
      B1h, B1l, p2Wh, p2Wl, p2B, nullptr, B2h, B2l, MLP_, MLP_, MLP_);
  k_mgemm<0, 0><<<dim3(1, T_ / 128), b256, 0, stream>>>(
      B2h, B2l, p3Wh, p3Wl, p3B, (float*)d_out, nullptr, nullptr, MLP_, ACT_, ACT_);
}